// Round 10
// baseline (382.026 us; speedup 1.0000x reference)
//
#include <hip/hip_runtime.h>
#include <math.h>

// ConditionalCNF log_prob, MFMA version, round 10.
// Round-9 base + transposed GEMMs: MFMA operands swapped (W as A, X as B) for the
// cr-GEMM / layer 1 / layer 2, so D comes out [hidden=quad*4+reg][batch=l15] and each
// lane's 4 epilogue values are contiguous in k -> one ds_write_b64 instead of four
// ds_write_b16 (96 scalar -> 24 vector LDS writes per wave-stage; kills the
// same-dword b16 write serialization seen as 1.11e7 SQ_LDS_BANK_CONFLICT).

#define DTc (-0.1f)

typedef __attribute__((ext_vector_type(8))) short bf16x8;
typedef __attribute__((ext_vector_type(8))) unsigned short u16x8;
typedef __attribute__((ext_vector_type(4))) float f32x4;

#define MFMA16(a, b, c) __builtin_amdgcn_mfma_f32_16x16x32_bf16((a), (b), (c), 0, 0, 0)

__device__ __forceinline__ unsigned short f2bf(float x) {
    union { float f; unsigned int u; } c; c.f = x;
    unsigned int r = c.u + 0x7FFFu + ((c.u >> 16) & 1u);   // RNE
    return (unsigned short)(r >> 16);
}

__device__ __forceinline__ unsigned int pk2bf(float lo, float hi) {
#if __has_builtin(__builtin_amdgcn_cvt_pk_bf16_f32)
    auto v = __builtin_amdgcn_cvt_pk_bf16_f32(lo, hi);     // v_cvt_pk_bf16_f32 (RNE)
    return __builtin_bit_cast(unsigned int, v);
#else
    return (unsigned int)f2bf(lo) | ((unsigned int)f2bf(hi) << 16);
#endif
}

// exact-GELU (erf) + derivative via A&S 7.1.25 3-term rational erf, sharing
// exp(-x^2/2) with the pdf. |erf err| <= 2.5e-5 << bf16 activation rounding.
__device__ __forceinline__ void gelu_both(float x, float& gv, float& dv) {
    float z  = fabsf(x) * 0.70710678118654752f;
    float e  = __builtin_amdgcn_exp2f(x * x * -0.72134752044448170f);  // exp(-x^2/2)
    float t  = __builtin_amdgcn_rcpf(__builtin_fmaf(0.47047f, z, 1.0f));
    float p  = t * (0.1740121f + t * (-0.0479399f + t * 0.3739278f));  // 0.5*(a1 t+a2 t^2+a3 t^3)
    float ch = p * e;                                                  // 0.5*erfc(z)
    float cdf = (x >= 0.0f) ? (1.0f - ch) : ch;
    gv = x * cdf;
    dv = __builtin_fmaf(0.39894228040143268f * x, e, cdf);
}

// ---------------- weight repack: fp32 -> bf16 fragments in ws ----------------
// Fragment layout [idx=lane&15][k=(lane>>4)*8+j] is identical for A and B operands;
// these buffers are used as the A operand (idx = hidden unit n) after the swap.
// w2f : [kb(6)][nt(12)][lane(64)][8]   frag[n][k]=W2[k][n]
// w1yf: [nt(12)][lane(64)][8]          k<16 -> W1[k][n]; k==16 -> W1[272][n]; else 0
// w1cf: [kb(8)][nt(12)][lane(64)][8]   frag[n][k]=W1[16+k][n]
// w3f : [kb(6)][lane(64)][8]           frag[d][k]=W3[k][d], d=lane&15 (B operand, layer 3)
__global__ void repack_kernel(const float* __restrict__ W1, const float* __restrict__ W2,
                              const float* __restrict__ W3,
                              unsigned short* __restrict__ w2f, unsigned short* __restrict__ w1yf,
                              unsigned short* __restrict__ w1cf, unsigned short* __restrict__ w3fg) {
    int t = blockIdx.x * 256 + threadIdx.x;
    u16x8 v;
    if (t < 4608) {
        int kb = t / 768, rem = t % 768, nt = rem / 64, lane = rem % 64;
        int n = nt * 16 + (lane & 15), k0 = kb * 32 + (lane >> 4) * 8;
        #pragma unroll
        for (int j = 0; j < 8; ++j) v[j] = f2bf(W2[(k0 + j) * 192 + n]);
        *(u16x8*)(w2f + t * 8) = v;
    } else if (t < 5376) {
        int i2 = t - 4608, nt = i2 / 64, lane = i2 % 64;
        int n = nt * 16 + (lane & 15), k0 = (lane >> 4) * 8;
        #pragma unroll
        for (int j = 0; j < 8; ++j) {
            int k = k0 + j;
            v[j] = (k < 16) ? f2bf(W1[k * 192 + n])
                 : (k == 16) ? f2bf(W1[272 * 192 + n]) : (unsigned short)0;
        }
        *(u16x8*)(w1yf + i2 * 8) = v;
    } else if (t < 11520) {
        int i3 = t - 5376, kb = i3 / 768, rem = i3 % 768, nt = rem / 64, lane = rem % 64;
        int n = nt * 16 + (lane & 15), k0 = kb * 32 + (lane >> 4) * 8;
        #pragma unroll
        for (int j = 0; j < 8; ++j) v[j] = f2bf(W1[(16 + k0 + j) * 192 + n]);
        *(u16x8*)(w1cf + i3 * 8) = v;
    } else if (t < 11904) {
        int i4 = t - 11520, kb = i4 / 64, lane = i4 % 64;
        int n = lane & 15, k0 = kb * 32 + (lane >> 4) * 8;
        #pragma unroll
        for (int j = 0; j < 8; ++j) v[j] = f2bf(W3[(k0 + j) * 16 + n]);
        *(u16x8*)(w3fg + i4 * 8) = v;
    }
}

// ---------------- main kernel ----------------
__global__ __launch_bounds__(256, 2) void cnf_mfma(
    const float* __restrict__ theta, const float* __restrict__ hctx,
    const float* __restrict__ eps,   const float* __restrict__ b1,
    const float* __restrict__ b2,    const float* __restrict__ b3,
    const unsigned short* __restrict__ w2f, const unsigned short* __restrict__ w1yf,
    const unsigned short* __restrict__ w1cf, const unsigned short* __restrict__ w3fg,
    float* __restrict__ out)
{
    __shared__ __align__(16) unsigned short Ys[64 * 24];   // rows 0-31 y, 32-63 e; k 0..15 only
    __shared__ __align__(16) unsigned short Xa0[64 * 200]; // h1/dh1 (aliased as Hs at init)
    __shared__ __align__(16) unsigned short Xa1[64 * 200]; // h2/dh2
    __shared__ __align__(16) float ebf[2][512];            // fp32 eps, double-buffered
    __shared__ float trx[32];

    const int tid  = threadIdx.x;
    const int wave = tid >> 6, lane = tid & 63;
    const int l15  = lane & 15, quad = lane >> 4;
    const int r0   = blockIdx.x * 32;
    const int ntg0 = wave * 3;
    const int mtw  = wave & 1;      // which fwd m-tile this wave owns in layer 3

    // stage h -> Hs (alias Xa0), stride 264 bf16, float4 global reads
    unsigned short* Hs = Xa0;
    for (int t4 = tid; t4 < 2048; t4 += 256) {
        int r = t4 >> 6, k = (t4 & 63) * 4;
        float4 v = *(const float4*)(hctx + (long)(r0 + r) * 256 + k);
        *(uint2*)(&Hs[r * 264 + k]) = make_uint2(pk2bf(v.x, v.y), pk2bf(v.z, v.w));
    }

    // eps register prefetch (waves 2,3): 4 elems/lane, float4 coalesced
    const int  ek = ((wave - 2) * 64 + lane) * 4;          // 0..508, valid for wave>=2
    const int  er = ek >> 4, ed = ek & 15;
    const long epsBase = (long)r0 * 16 + ek;
    float4 epr;
    if (wave >= 2) epr = *(const float4*)(eps + epsBase);  // sg = 0

    // per-wave constant fragments / scalars
    bf16x8 b1yfr[3], w3fr[6];
    #pragma unroll
    for (int nt = 0; nt < 3; ++nt)
        b1yfr[nt] = *reinterpret_cast<const bf16x8*>(w1yf + ((ntg0 + nt) * 64 + lane) * 8);
    #pragma unroll
    for (int kb = 0; kb < 6; ++kb)
        w3fr[kb] = *reinterpret_cast<const bf16x8*>(w3fg + (kb * 64 + lane) * 8);
    // bias seeds in transposed-D layout: value per (nt, i): hidden n = (ntg0+nt)*16+quad*4+i
    f32x4 b2s[3];
    #pragma unroll
    for (int nt = 0; nt < 3; ++nt)
        #pragma unroll
        for (int i = 0; i < 4; ++i)
            b2s[nt][i] = b2[(ntg0 + nt) * 16 + quad * 4 + i];
    const float b3r = b3[l15];

    // waves 0,1: integration state for own m-tile: yreg[i] = y[r = mtw*16+quad*4+i][d = l15]
    float yreg[4];
    if (wave < 2) {
        #pragma unroll
        for (int i = 0; i < 4; ++i)
            yreg[i] = theta[(r0 + mtw * 16 + quad * 4 + i) * 16 + l15];
    }

    __syncthreads();   // Hs visible

    // ---- c = b1 + h @ W1ctx (transposed D: [hidden=quad*4+i][batch=l15]) ----
    float cr[2][3][4];
    {
        f32x4 ca[2][3] = {};
        #pragma unroll
        for (int kb = 0; kb < 8; ++kb) {
            bf16x8 xf[2];
            #pragma unroll
            for (int mt = 0; mt < 2; ++mt)
                xf[mt] = *reinterpret_cast<const bf16x8*>(&Hs[(mt * 16 + l15) * 264 + kb * 32 + quad * 8]);
            #pragma unroll
            for (int nt = 0; nt < 3; ++nt) {
                bf16x8 wf = *reinterpret_cast<const bf16x8*>(w1cf + ((kb * 12 + ntg0 + nt) * 64 + lane) * 8);
                #pragma unroll
                for (int mt = 0; mt < 2; ++mt)
                    ca[mt][nt] = MFMA16(wf, xf[mt], ca[mt][nt]);   // W as A, X as B -> D^T
            }
        }
        #pragma unroll
        for (int mt = 0; mt < 2; ++mt)
            #pragma unroll
            for (int nt = 0; nt < 3; ++nt)
                #pragma unroll
                for (int i = 0; i < 4; ++i)
                    cr[mt][nt][i] = ca[mt][nt][i] + b1[(ntg0 + nt) * 16 + quad * 4 + i];
    }

    // ---- initial staging for sg=0 ----
    if (wave < 2) {
        #pragma unroll
        for (int i = 0; i < 4; ++i)
            Ys[(mtw * 16 + quad * 4 + i) * 24 + l15] = f2bf(yreg[i]);
    }
    if (wave >= 2) {
        *(uint2*)(&Ys[(32 + er) * 24 + ed]) = make_uint2(pk2bf(epr.x, epr.y), pk2bf(epr.z, epr.w));
        *(float4*)(&ebf[0][ek]) = epr;
        epr = *(const float4*)(eps + (long)1 * 262144 + epsBase);   // prefetch sg=1
    }

    float F1[4], F2[4], F3[4];
    float tracc[4] = {0.f, 0.f, 0.f, 0.f};   // waves 2,3: per-lane (d=l15) trace partials

    for (int sg = 0; sg < 40; ++sg) {
        const int sub = sg & 3;
        const float ts = 1.0f + DTc * (float)(sg >> 2) + DTc * ((float)sub * (1.0f / 3.0f));
        const short tsb = (short)f2bf(ts);

        __syncthreads();   // B1: Ys/ebf staged

        // ---- layer 1 (K=32; k16 = t slot, k17..31 zero) + GELU -> Xa0 ----
        {
            bf16x8 xf[4];
            if (quad < 2) {
                #pragma unroll
                for (int mt = 0; mt < 4; ++mt)
                    xf[mt] = *reinterpret_cast<const bf16x8*>(&Ys[(mt * 16 + l15) * 24 + quad * 8]);
            } else {
                #pragma unroll
                for (int mt = 0; mt < 4; ++mt) xf[mt] = bf16x8{};
                if (quad == 2) { xf[0][0] = tsb; xf[1][0] = tsb; }   // fwd rows get t; tangent stay 0
            }
            f32x4 acc[4][3];
            #pragma unroll
            for (int nt = 0; nt < 3; ++nt) {
                #pragma unroll
                for (int mt = 0; mt < 2; ++mt)
                    acc[mt][nt] = f32x4{cr[mt][nt][0], cr[mt][nt][1], cr[mt][nt][2], cr[mt][nt][3]};
                acc[2][nt] = f32x4{};
                acc[3][nt] = f32x4{};
            }
            #pragma unroll
            for (int nt = 0; nt < 3; ++nt)
                #pragma unroll
                for (int mt = 0; mt < 4; ++mt)
                    acc[mt][nt] = MFMA16(b1yfr[nt], xf[mt], acc[mt][nt]);   // transposed D
            #pragma unroll
            for (int nt = 0; nt < 3; ++nt) {
                int n0 = (ntg0 + nt) * 16 + quad * 4;
                #pragma unroll
                for (int mt = 0; mt < 2; ++mt) {
                    float gvv[4], dvv[4];
                    #pragma unroll
                    for (int i = 0; i < 4; ++i) {
                        float gv, dv; gelu_both(acc[mt][nt][i], gv, dv);
                        gvv[i] = gv; dvv[i] = dv * acc[mt + 2][nt][i];
                    }
                    // lane's 4 values are contiguous in k -> single b64 write each
                    *(uint2*)(&Xa0[(mt * 16 + l15) * 200 + n0]) =
                        make_uint2(pk2bf(gvv[0], gvv[1]), pk2bf(gvv[2], gvv[3]));
                    *(uint2*)(&Xa0[((mt + 2) * 16 + l15) * 200 + n0]) =
                        make_uint2(pk2bf(dvv[0], dvv[1]), pk2bf(dvv[2], dvv[3]));
                }
            }
        }
        __syncthreads();   // B2: Xa0 ready

        // ---- layer 2 (K=192) -> Xa1 ----
        {
            f32x4 acc2[4][3];
            #pragma unroll
            for (int nt = 0; nt < 3; ++nt) {
                acc2[0][nt] = b2s[nt];
                acc2[1][nt] = b2s[nt];
                acc2[2][nt] = f32x4{};
                acc2[3][nt] = f32x4{};
            }
            #pragma unroll
            for (int kb = 0; kb < 6; ++kb) {
                bf16x8 xA[4];
                #pragma unroll
                for (int mt = 0; mt < 4; ++mt)
                    xA[mt] = *reinterpret_cast<const bf16x8*>(&Xa0[(mt * 16 + l15) * 200 + kb * 32 + quad * 8]);
                #pragma unroll
                for (int nt = 0; nt < 3; ++nt) {
                    bf16x8 wf = *reinterpret_cast<const bf16x8*>(w2f + ((kb * 12 + ntg0 + nt) * 64 + lane) * 8);
                    #pragma unroll
                    for (int mt = 0; mt < 4; ++mt)
                        acc2[mt][nt] = MFMA16(wf, xA[mt], acc2[mt][nt]);   // transposed D
                }
            }
            #pragma unroll
            for (int nt = 0; nt < 3; ++nt) {
                int n0 = (ntg0 + nt) * 16 + quad * 4;
                #pragma unroll
                for (int mt = 0; mt < 2; ++mt) {
                    float gvv[4], dvv[4];
                    #pragma unroll
                    for (int i = 0; i < 4; ++i) {
                        float gv, dv; gelu_both(acc2[mt][nt][i], gv, dv);
                        gvv[i] = gv; dvv[i] = dv * acc2[mt + 2][nt][i];
                    }
                    *(uint2*)(&Xa1[(mt * 16 + l15) * 200 + n0]) =
                        make_uint2(pk2bf(gvv[0], gvv[1]), pk2bf(gvv[2], gvv[3]));
                    *(uint2*)(&Xa1[((mt + 2) * 16 + l15) * 200 + n0]) =
                        make_uint2(pk2bf(dvv[0], dvv[1]), pk2bf(dvv[2], dvv[3]));
                }
            }
        }
        __syncthreads();   // B3: Xa1 ready

        // ---- layer 3 (untransposed: D[m=batch][d]), split 4 ways ----
        {
            f32x4 acc3 = (wave < 2) ? f32x4{b3r, b3r, b3r, b3r} : f32x4{};
            const unsigned short* src = &Xa1[(wave * 16 + l15) * 200];
            #pragma unroll
            for (int kb = 0; kb < 6; ++kb)
                acc3 = MFMA16(*reinterpret_cast<const bf16x8*>(src + kb * 32 + quad * 8), w3fr[kb], acc3);

            if (wave < 2) {
                // forward rows: Fc = acc3 (b3 seeded); RK4 state update + next-y staging
                if (sub == 0) {
                    #pragma unroll
                    for (int i = 0; i < 4; ++i) F1[i] = acc3[i];
                } else if (sub == 1) {
                    #pragma unroll
                    for (int i = 0; i < 4; ++i) F2[i] = acc3[i];
                } else if (sub == 2) {
                    #pragma unroll
                    for (int i = 0; i < 4; ++i) F3[i] = acc3[i];
                } else {
                    #pragma unroll
                    for (int i = 0; i < 4; ++i)
                        yreg[i] += DTc * 0.125f * (F1[i] + 3.0f * (F2[i] + F3[i]) + acc3[i]);
                }
                if (sg < 39) {
                    const int sub2 = (sg + 1) & 3;
                    #pragma unroll
                    for (int i = 0; i < 4; ++i) {
                        float ys = yreg[i];
                        if (sub2 == 1)      ys += DTc * (1.0f / 3.0f) * F1[i];
                        else if (sub2 == 2) ys += DTc * (F2[i] - (1.0f / 3.0f) * F1[i]);
                        else if (sub2 == 3) ys += DTc * (F1[i] - F2[i] + F3[i]);
                        Ys[(mtw * 16 + quad * 4 + i) * 24 + l15] = f2bf(ys);
                    }
                }
            } else {
                // tangent rows: per-lane trace partial (d = l15), reduced after the loop
                const float csub = (sub == 1 || sub == 2) ? 3.0f : 1.0f;
                #pragma unroll
                for (int i = 0; i < 4; ++i) {
                    int r = mtw * 16 + quad * 4 + i;
                    tracc[i] = __builtin_fmaf(csub * ebf[sg & 1][r * 16 + l15], acc3[i], tracc[i]);
                }
                // stage next eps
                if (sg < 39) {
                    *(uint2*)(&Ys[(32 + er) * 24 + ed]) = make_uint2(pk2bf(epr.x, epr.y), pk2bf(epr.z, epr.w));
                    *(float4*)(&ebf[(sg + 1) & 1][ek]) = epr;
                    if (sg < 38)
                        epr = *(const float4*)(eps + (long)(sg + 2) * 262144 + epsBase);
                }
            }
        }
    }

    // ---- final trace reduction (waves 2,3) -> trx ----
    if (wave >= 2) {
        #pragma unroll
        for (int i = 0; i < 4; ++i) {
            float v = tracc[i];
            v += __shfl_xor(v, 1);
            v += __shfl_xor(v, 2);
            v += __shfl_xor(v, 4);
            v += __shfl_xor(v, 8);
            if (l15 == 0) trx[mtw * 16 + quad * 4 + i] = v;
        }
    }
    __syncthreads();

    // ---- output (waves 0,1 hold final y for their m-tile) ----
    if (wave < 2) {
        #pragma unroll
        for (int i = 0; i < 4; ++i) {
            float q = yreg[i] * yreg[i];
            q += __shfl_xor(q, 1);
            q += __shfl_xor(q, 2);
            q += __shfl_xor(q, 4);
            q += __shfl_xor(q, 8);
            if (l15 == 0) {
                int r = mtw * 16 + quad * 4 + i;
                out[r0 + r] = -0.5f * q - 14.7030165313f + DTc * 0.125f * trx[r];
            }
        }
    }
}

extern "C" void kernel_launch(void* const* d_in, const int* in_sizes, int n_in,
                              void* d_out, int out_size, void* d_ws, size_t ws_size,
                              hipStream_t stream) {
    const float* theta = (const float*)d_in[0];
    const float* hctx  = (const float*)d_in[1];
    const float* eps   = (const float*)d_in[2];
    const float* W1    = (const float*)d_in[3];
    const float* b1    = (const float*)d_in[4];
    const float* W2    = (const float*)d_in[5];
    const float* b2    = (const float*)d_in[6];
    const float* W3    = (const float*)d_in[7];
    const float* b3    = (const float*)d_in[8];
    float* outp = (float*)d_out;

    unsigned short* w2f  = (unsigned short*)d_ws;   // 36864 elems
    unsigned short* w1yf = w2f + 36864;             // 6144
    unsigned short* w1cf = w1yf + 6144;             // 49152
    unsigned short* w3fg = w1cf + 49152;            // 3072

    hipLaunchKernelGGL(repack_kernel, dim3(47), dim3(256), 0, stream,
                       W1, W2, W3, w2f, w1yf, w1cf, w3fg);
    hipLaunchKernelGGL(cnf_mfma, dim3(512), dim3(256), 0, stream,
                       theta, hctx, eps, b1, b2, b3, w2f, w1yf, w1cf, w3fg, outp);
}

// Round 11
// 349.273 us; speedup vs baseline: 1.0938x; 1.0938x over previous
//
#include <hip/hip_runtime.h>
#include <math.h>

// ConditionalCNF log_prob, MFMA version, round 11.
// = round 9 (best known, 287 us) with the fp32 ebf buffer deleted: the trace dot
// reads the bf16 eps already staged in Ys rows 32..63 (2-way bank aliasing = free,
// vs ebf's 4-way). Zero register-pressure change. r10's transposed-epilogue family
// is abandoned (register cliff -> spill, twice).

#define DTc (-0.1f)

typedef __attribute__((ext_vector_type(8))) short bf16x8;
typedef __attribute__((ext_vector_type(8))) unsigned short u16x8;
typedef __attribute__((ext_vector_type(4))) float f32x4;

#define MFMA16(a, b, c) __builtin_amdgcn_mfma_f32_16x16x32_bf16((a), (b), (c), 0, 0, 0)

__device__ __forceinline__ unsigned short f2bf(float x) {
    union { float f; unsigned int u; } c; c.f = x;
    unsigned int r = c.u + 0x7FFFu + ((c.u >> 16) & 1u);   // RNE
    return (unsigned short)(r >> 16);
}

__device__ __forceinline__ unsigned int pk2bf(float lo, float hi) {
#if __has_builtin(__builtin_amdgcn_cvt_pk_bf16_f32)
    auto v = __builtin_amdgcn_cvt_pk_bf16_f32(lo, hi);     // v_cvt_pk_bf16_f32 (RNE)
    return __builtin_bit_cast(unsigned int, v);
#else
    return (unsigned int)f2bf(lo) | ((unsigned int)f2bf(hi) << 16);
#endif
}

// exact-GELU (erf) + derivative via A&S 7.1.25 3-term rational erf, sharing
// exp(-x^2/2) with the pdf. |erf err| <= 2.5e-5 << bf16 activation rounding.
__device__ __forceinline__ void gelu_both(float x, float& gv, float& dv) {
    float z  = fabsf(x) * 0.70710678118654752f;
    float e  = __builtin_amdgcn_exp2f(x * x * -0.72134752044448170f);  // exp(-x^2/2)
    float t  = __builtin_amdgcn_rcpf(__builtin_fmaf(0.47047f, z, 1.0f));
    float p  = t * (0.1740121f + t * (-0.0479399f + t * 0.3739278f));  // 0.5*(a1 t+a2 t^2+a3 t^3)
    float ch = p * e;                                                  // 0.5*erfc(z)
    float cdf = (x >= 0.0f) ? (1.0f - ch) : ch;
    gv = x * cdf;
    dv = __builtin_fmaf(0.39894228040143268f * x, e, cdf);
}

// ---------------- weight repack: fp32 -> bf16 B-fragments in ws ----------------
// w2f : [kb(6)][nt(12)][lane(64)][8]   B[n][k]=W2[k][n]
// w1yf: [nt(12)][lane(64)][8]          k<16 -> W1[k][n]; k==16 -> W1[272][n]; else 0
// w1cf: [kb(8)][nt(12)][lane(64)][8]   B[n][k]=W1[16+k][n]
// w3f : [kb(6)][lane(64)][8]           B[n][k]=W3[k][n], n=lane&15 (d)
__global__ void repack_kernel(const float* __restrict__ W1, const float* __restrict__ W2,
                              const float* __restrict__ W3,
                              unsigned short* __restrict__ w2f, unsigned short* __restrict__ w1yf,
                              unsigned short* __restrict__ w1cf, unsigned short* __restrict__ w3fg) {
    int t = blockIdx.x * 256 + threadIdx.x;
    u16x8 v;
    if (t < 4608) {
        int kb = t / 768, rem = t % 768, nt = rem / 64, lane = rem % 64;
        int n = nt * 16 + (lane & 15), k0 = kb * 32 + (lane >> 4) * 8;
        #pragma unroll
        for (int j = 0; j < 8; ++j) v[j] = f2bf(W2[(k0 + j) * 192 + n]);
        *(u16x8*)(w2f + t * 8) = v;
    } else if (t < 5376) {
        int i2 = t - 4608, nt = i2 / 64, lane = i2 % 64;
        int n = nt * 16 + (lane & 15), k0 = (lane >> 4) * 8;
        #pragma unroll
        for (int j = 0; j < 8; ++j) {
            int k = k0 + j;
            v[j] = (k < 16) ? f2bf(W1[k * 192 + n])
                 : (k == 16) ? f2bf(W1[272 * 192 + n]) : (unsigned short)0;
        }
        *(u16x8*)(w1yf + i2 * 8) = v;
    } else if (t < 11520) {
        int i3 = t - 5376, kb = i3 / 768, rem = i3 % 768, nt = rem / 64, lane = rem % 64;
        int n = nt * 16 + (lane & 15), k0 = kb * 32 + (lane >> 4) * 8;
        #pragma unroll
        for (int j = 0; j < 8; ++j) v[j] = f2bf(W1[(16 + k0 + j) * 192 + n]);
        *(u16x8*)(w1cf + i3 * 8) = v;
    } else if (t < 11904) {
        int i4 = t - 11520, kb = i4 / 64, lane = i4 % 64;
        int n = lane & 15, k0 = kb * 32 + (lane >> 4) * 8;
        #pragma unroll
        for (int j = 0; j < 8; ++j) v[j] = f2bf(W3[(k0 + j) * 16 + n]);
        *(u16x8*)(w3fg + i4 * 8) = v;
    }
}

// ---------------- main kernel ----------------
__global__ __launch_bounds__(256, 2) void cnf_mfma(
    const float* __restrict__ theta, const float* __restrict__ hctx,
    const float* __restrict__ eps,   const float* __restrict__ b1,
    const float* __restrict__ b2,    const float* __restrict__ b3,
    const unsigned short* __restrict__ w2f, const unsigned short* __restrict__ w1yf,
    const unsigned short* __restrict__ w1cf, const unsigned short* __restrict__ w3fg,
    float* __restrict__ out)
{
    __shared__ __align__(16) unsigned short Ys[64 * 24];   // rows 0-31 y, 32-63 e; k 0..15 only
    __shared__ __align__(16) unsigned short Xa0[64 * 200]; // h1/dh1 (aliased as Hs at init)
    __shared__ __align__(16) unsigned short Xa1[64 * 200]; // h2/dh2
    __shared__ float trx[32];

    const int tid  = threadIdx.x;
    const int wave = tid >> 6, lane = tid & 63;
    const int l15  = lane & 15, quad = lane >> 4;
    const int r0   = blockIdx.x * 32;
    const int ntg0 = wave * 3;
    const int mtw  = wave & 1;      // which m-tile this wave owns in layer 3

    // stage h -> Hs (alias Xa0), stride 264 bf16, float4 global reads
    unsigned short* Hs = Xa0;
    for (int t4 = tid; t4 < 2048; t4 += 256) {
        int r = t4 >> 6, k = (t4 & 63) * 4;
        float4 v = *(const float4*)(hctx + (long)(r0 + r) * 256 + k);
        *(uint2*)(&Hs[r * 264 + k]) = make_uint2(pk2bf(v.x, v.y), pk2bf(v.z, v.w));
    }

    // eps register prefetch (waves 2,3): 4 elems/lane, float4 coalesced
    const int  ek = ((wave - 2) * 64 + lane) * 4;          // 0..508, valid for wave>=2
    const int  er = ek >> 4, ed = ek & 15;
    const long epsBase = (long)r0 * 16 + ek;
    float4 epr;
    if (wave >= 2) epr = *(const float4*)(eps + epsBase);  // sg = 0

    // per-wave constant fragments / scalars
    bf16x8 b1yfr[3], w3fr[6];
    #pragma unroll
    for (int nt = 0; nt < 3; ++nt)
        b1yfr[nt] = *reinterpret_cast<const bf16x8*>(w1yf + ((ntg0 + nt) * 64 + lane) * 8);
    #pragma unroll
    for (int kb = 0; kb < 6; ++kb)
        w3fr[kb] = *reinterpret_cast<const bf16x8*>(w3fg + (kb * 64 + lane) * 8);
    float b2r[3], b1r[3];
    #pragma unroll
    for (int nt = 0; nt < 3; ++nt) {
        int n = (ntg0 + nt) * 16 + l15;
        b2r[nt] = b2[n];
        b1r[nt] = b1[n];
    }
    const float b3r = b3[l15];

    // waves 0,1: integration state for own m-tile: yreg[i] = y[r = mtw*16+quad*4+i][d = l15]
    float yreg[4];
    if (wave < 2) {
        #pragma unroll
        for (int i = 0; i < 4; ++i)
            yreg[i] = theta[(r0 + mtw * 16 + quad * 4 + i) * 16 + l15];
    }

    __syncthreads();   // Hs visible

    // ---- c = b1 + h @ W1ctx, in registers (fwd rows only, mt 0-1) ----
    float cr[2][3][4];
    {
        f32x4 ca[2][3] = {};
        #pragma unroll
        for (int kb = 0; kb < 8; ++kb) {
            bf16x8 af[2];
            #pragma unroll
            for (int mt = 0; mt < 2; ++mt)
                af[mt] = *reinterpret_cast<const bf16x8*>(&Hs[(mt * 16 + l15) * 264 + kb * 32 + quad * 8]);
            #pragma unroll
            for (int nt = 0; nt < 3; ++nt) {
                bf16x8 bf = *reinterpret_cast<const bf16x8*>(w1cf + ((kb * 12 + ntg0 + nt) * 64 + lane) * 8);
                #pragma unroll
                for (int mt = 0; mt < 2; ++mt)
                    ca[mt][nt] = MFMA16(af[mt], bf, ca[mt][nt]);
            }
        }
        #pragma unroll
        for (int mt = 0; mt < 2; ++mt)
            #pragma unroll
            for (int nt = 0; nt < 3; ++nt)
                #pragma unroll
                for (int i = 0; i < 4; ++i)
                    cr[mt][nt][i] = ca[mt][nt][i] + b1r[nt];
    }

    // ---- initial staging for sg=0 ----
    if (wave < 2) {
        #pragma unroll
        for (int i = 0; i < 4; ++i)
            Ys[(mtw * 16 + quad * 4 + i) * 24 + l15] = f2bf(yreg[i]);
    }
    if (wave >= 2) {
        *(uint2*)(&Ys[(32 + er) * 24 + ed]) = make_uint2(pk2bf(epr.x, epr.y), pk2bf(epr.z, epr.w));
        epr = *(const float4*)(eps + (long)1 * 262144 + epsBase);   // prefetch sg=1
    }

    float F1[4], F2[4], F3[4];
    float tracc[4] = {0.f, 0.f, 0.f, 0.f};   // waves 2,3: per-lane (d=l15) trace partials

    for (int sg = 0; sg < 40; ++sg) {
        const int sub = sg & 3;
        const float ts = 1.0f + DTc * (float)(sg >> 2) + DTc * ((float)sub * (1.0f / 3.0f));
        const short tsb = (short)f2bf(ts);

        __syncthreads();   // B1: Ys staged

        // ---- layer 1 (K=32; k16 = t slot, k17..31 zero) + GELU -> Xa0 ----
        {
            bf16x8 af[4];
            if (quad < 2) {
                #pragma unroll
                for (int mt = 0; mt < 4; ++mt)
                    af[mt] = *reinterpret_cast<const bf16x8*>(&Ys[(mt * 16 + l15) * 24 + quad * 8]);
            } else {
                #pragma unroll
                for (int mt = 0; mt < 4; ++mt) af[mt] = bf16x8{};
                if (quad == 2) { af[0][0] = tsb; af[1][0] = tsb; }   // fwd rows get t; tangent stay 0
            }
            f32x4 acc[4][3];
            #pragma unroll
            for (int nt = 0; nt < 3; ++nt) {
                #pragma unroll
                for (int mt = 0; mt < 2; ++mt)
                    acc[mt][nt] = f32x4{cr[mt][nt][0], cr[mt][nt][1], cr[mt][nt][2], cr[mt][nt][3]};
                acc[2][nt] = f32x4{};
                acc[3][nt] = f32x4{};
            }
            #pragma unroll
            for (int nt = 0; nt < 3; ++nt)
                #pragma unroll
                for (int mt = 0; mt < 4; ++mt)
                    acc[mt][nt] = MFMA16(af[mt], b1yfr[nt], acc[mt][nt]);
            #pragma unroll
            for (int nt = 0; nt < 3; ++nt) {
                int n = (ntg0 + nt) * 16 + l15;
                #pragma unroll
                for (int mt = 0; mt < 2; ++mt) {
                    float gvv[4], dvv[4];
                    #pragma unroll
                    for (int i = 0; i < 4; ++i) {
                        float gv, dv; gelu_both(acc[mt][nt][i], gv, dv);
                        gvv[i] = gv; dvv[i] = dv * acc[mt + 2][nt][i];
                    }
                    unsigned int p0 = pk2bf(gvv[0], gvv[1]), p1 = pk2bf(gvv[2], gvv[3]);
                    unsigned int q0 = pk2bf(dvv[0], dvv[1]), q1 = pk2bf(dvv[2], dvv[3]);
                    int ba = (mt * 16 + quad * 4) * 200 + n;
                    Xa0[ba]          = (unsigned short)p0;
                    Xa0[ba + 200]    = (unsigned short)(p0 >> 16);
                    Xa0[ba + 400]    = (unsigned short)p1;
                    Xa0[ba + 600]    = (unsigned short)(p1 >> 16);
                    Xa0[ba + 6400]   = (unsigned short)q0;
                    Xa0[ba + 6600]   = (unsigned short)(q0 >> 16);
                    Xa0[ba + 6800]   = (unsigned short)q1;
                    Xa0[ba + 7000]   = (unsigned short)(q1 >> 16);
                }
            }
        }
        __syncthreads();   // B2: Xa0 ready

        // ---- layer 2 (K=192) -> Xa1 ----
        {
            f32x4 acc2[4][3];
            #pragma unroll
            for (int nt = 0; nt < 3; ++nt) {
                acc2[0][nt] = f32x4{b2r[nt], b2r[nt], b2r[nt], b2r[nt]};
                acc2[1][nt] = acc2[0][nt];
                acc2[2][nt] = f32x4{};
                acc2[3][nt] = f32x4{};
            }
            #pragma unroll
            for (int kb = 0; kb < 6; ++kb) {
                bf16x8 aA[4];
                #pragma unroll
                for (int mt = 0; mt < 4; ++mt)
                    aA[mt] = *reinterpret_cast<const bf16x8*>(&Xa0[(mt * 16 + l15) * 200 + kb * 32 + quad * 8]);
                #pragma unroll
                for (int nt = 0; nt < 3; ++nt) {
                    bf16x8 bf = *reinterpret_cast<const bf16x8*>(w2f + ((kb * 12 + ntg0 + nt) * 64 + lane) * 8);
                    #pragma unroll
                    for (int mt = 0; mt < 4; ++mt)
                        acc2[mt][nt] = MFMA16(aA[mt], bf, acc2[mt][nt]);
                }
            }
            #pragma unroll
            for (int nt = 0; nt < 3; ++nt) {
                int n = (ntg0 + nt) * 16 + l15;
                #pragma unroll
                for (int mt = 0; mt < 2; ++mt) {
                    float gvv[4], dvv[4];
                    #pragma unroll
                    for (int i = 0; i < 4; ++i) {
                        float gv, dv; gelu_both(acc2[mt][nt][i], gv, dv);
                        gvv[i] = gv; dvv[i] = dv * acc2[mt + 2][nt][i];
                    }
                    unsigned int p0 = pk2bf(gvv[0], gvv[1]), p1 = pk2bf(gvv[2], gvv[3]);
                    unsigned int q0 = pk2bf(dvv[0], dvv[1]), q1 = pk2bf(dvv[2], dvv[3]);
                    int ba = (mt * 16 + quad * 4) * 200 + n;
                    Xa1[ba]          = (unsigned short)p0;
                    Xa1[ba + 200]    = (unsigned short)(p0 >> 16);
                    Xa1[ba + 400]    = (unsigned short)p1;
                    Xa1[ba + 600]    = (unsigned short)(p1 >> 16);
                    Xa1[ba + 6400]   = (unsigned short)q0;
                    Xa1[ba + 6600]   = (unsigned short)(q0 >> 16);
                    Xa1[ba + 6800]   = (unsigned short)q1;
                    Xa1[ba + 7000]   = (unsigned short)(q1 >> 16);
                }
            }
        }
        __syncthreads();   // B3: Xa1 ready

        // ---- layer 3, split 4 ways: wave w owns rows w*16+l15 ----
        {
            f32x4 acc3 = (wave < 2) ? f32x4{b3r, b3r, b3r, b3r} : f32x4{};
            const unsigned short* src = &Xa1[(wave * 16 + l15) * 200];
            #pragma unroll
            for (int kb = 0; kb < 6; ++kb)
                acc3 = MFMA16(*reinterpret_cast<const bf16x8*>(src + kb * 32 + quad * 8), w3fr[kb], acc3);

            if (wave < 2) {
                // forward rows: Fc = acc3 (b3 seeded); RK4 state update + next-y staging
                if (sub == 0) {
                    #pragma unroll
                    for (int i = 0; i < 4; ++i) F1[i] = acc3[i];
                } else if (sub == 1) {
                    #pragma unroll
                    for (int i = 0; i < 4; ++i) F2[i] = acc3[i];
                } else if (sub == 2) {
                    #pragma unroll
                    for (int i = 0; i < 4; ++i) F3[i] = acc3[i];
                } else {
                    #pragma unroll
                    for (int i = 0; i < 4; ++i)
                        yreg[i] += DTc * 0.125f * (F1[i] + 3.0f * (F2[i] + F3[i]) + acc3[i]);
                }
                if (sg < 39) {
                    const int sub2 = (sg + 1) & 3;
                    #pragma unroll
                    for (int i = 0; i < 4; ++i) {
                        float ys = yreg[i];
                        if (sub2 == 1)      ys += DTc * (1.0f / 3.0f) * F1[i];
                        else if (sub2 == 2) ys += DTc * (F2[i] - (1.0f / 3.0f) * F1[i]);
                        else if (sub2 == 3) ys += DTc * (F1[i] - F2[i] + F3[i]);
                        Ys[(mtw * 16 + quad * 4 + i) * 24 + l15] = f2bf(ys);
                    }
                }
            } else {
                // tangent rows: per-lane trace partial (d = l15) using the bf16 eps in Ys.
                // Reads precede this wave's own staging writes to the same rows (same-wave
                // LDS ordering); other waves' rows are disjoint.
                const float csub = (sub == 1 || sub == 2) ? 3.0f : 1.0f;
                #pragma unroll
                for (int i = 0; i < 4; ++i) {
                    int r = mtw * 16 + quad * 4 + i;
                    unsigned int eu = (unsigned int)Ys[(32 + r) * 24 + l15] << 16;
                    float ev = __builtin_bit_cast(float, eu);
                    tracc[i] = __builtin_fmaf(csub * ev, acc3[i], tracc[i]);
                }
                // stage next eps
                if (sg < 39) {
                    *(uint2*)(&Ys[(32 + er) * 24 + ed]) = make_uint2(pk2bf(epr.x, epr.y), pk2bf(epr.z, epr.w));
                    if (sg < 38)
                        epr = *(const float4*)(eps + (long)(sg + 2) * 262144 + epsBase);
                }
            }
        }
    }

    // ---- final trace reduction (waves 2,3) -> trx ----
    if (wave >= 2) {
        #pragma unroll
        for (int i = 0; i < 4; ++i) {
            float v = tracc[i];
            v += __shfl_xor(v, 1);
            v += __shfl_xor(v, 2);
            v += __shfl_xor(v, 4);
            v += __shfl_xor(v, 8);
            if (l15 == 0) trx[mtw * 16 + quad * 4 + i] = v;
        }
    }
    __syncthreads();

    // ---- output (waves 0,1 hold final y for their m-tile) ----
    if (wave < 2) {
        #pragma unroll
        for (int i = 0; i < 4; ++i) {
            float q = yreg[i] * yreg[i];
            q += __shfl_xor(q, 1);
            q += __shfl_xor(q, 2);
            q += __shfl_xor(q, 4);
            q += __shfl_xor(q, 8);
            if (l15 == 0) {
                int r = mtw * 16 + quad * 4 + i;
                out[r0 + r] = -0.5f * q - 14.7030165313f + DTc * 0.125f * trx[r];
            }
        }
    }
}

extern "C" void kernel_launch(void* const* d_in, const int* in_sizes, int n_in,
                              void* d_out, int out_size, void* d_ws, size_t ws_size,
                              hipStream_t stream) {
    const float* theta = (const float*)d_in[0];
    const float* hctx  = (const float*)d_in[1];
    const float* eps   = (const float*)d_in[2];
    const float* W1    = (const float*)d_in[3];
    const float* b1    = (const float*)d_in[4];
    const float* W2    = (const float*)d_in[5];
    const float* b2    = (const float*)d_in[6];
    const float* W3    = (const float*)d_in[7];
    const float* b3    = (const float*)d_in[8];
    float* outp = (float*)d_out;

    unsigned short* w2f  = (unsigned short*)d_ws;   // 36864 elems
    unsigned short* w1yf = w2f + 36864;             // 6144
    unsigned short* w1cf = w1yf + 6144;             // 49152
    unsigned short* w3fg = w1cf + 49152;            // 3072

    hipLaunchKernelGGL(repack_kernel, dim3(47), dim3(256), 0, stream,
                       W1, W2, W3, w2f, w1yf, w1cf, w3fg);
    hipLaunchKernelGGL(cnf_mfma, dim3(512), dim3(256), 0, stream,
                       theta, hctx, eps, b1, b2, b3, w2f, w1yf, w1cf, w3fg, outp);
}